// Round 11
// baseline (246.938 us; speedup 1.0000x reference)
//
#include <hip/hip_runtime.h>
#include <math.h>
#include <stdint.h>

#define NBATCH 2048
#define NSLOT 32

struct Args {
    const float* x;
    const float* W[7];
    const float* G[7];
    const float* Bt[7];
    const float* WFC;
    float* out;
    float* bufA;      // 29,425,664 B
    float* bufB;      // 13,631,488 B
    double* stats;    // 20224 8-byte slots (L1 region f64; L2..L7 regions int64)
    float* wsc;       // 321 floats
    uint32_t* wmb;    // 2260 words (lives in d_out, dead until fc)
};

__device__ __forceinline__ float signf(float v) {
    return (v > 0.f) ? 1.f : ((v < 0.f) ? -1.f : 0.f);
}

// ---------------- setup: zero stats, weight scales, weight bit-pack ---------
// wmb layout (words): bin2@0 (12x3 byte-packed), bin3@36 (32x{E,O}x5 u16-pair),
// bin4@356 (64x7), bin5@804 (64x5 u64), bin6@1444 (64x3 u64), bin7@1828 (72x3 u64).
// CIN=64: bit 16*(c&3)+(c>>2); CIN=32: bit 8*(c&3)+(c>>2); CIN<=12: bit c.
__global__ __launch_bounds__(256) void k_setup(Args a) {
    const int blk = blockIdx.x, tid = threadIdx.x;
    for (int i = blk * 256 + tid; i < NSLOT * 632; i += 391 * 256) a.stats[i] = 0.0;

    if (blk < 321 && tid < 64) {   // mean|w| per output channel
        const int cum[9] = {0,8,20,52,116,180,244,316,321};
        const int per[8] = {16,96,108,224,320,192,192,216};
        const float* wsrc[8] = {a.W[0],a.W[1],a.W[2],a.W[3],a.W[4],a.W[5],a.W[6],a.WFC};
        int o = blk, L = 0;
        while (L < 7 && o >= cum[L + 1]) ++L;
        const int oo = o - cum[L], p = per[L];
        const float* wo = wsrc[L] + (size_t)oo * p;
        float s = 0.f;
        for (int i = tid; i < p; i += 64) s += fabsf(wo[i]);
        #pragma unroll
        for (int off = 32; off; off >>= 1) s += __shfl_down(s, off);
        if (tid == 0) a.wsc[o] = s / (float)p;
    }

    // blocks 384..388: generic sign pack for bin4..bin7
    const int gid = (blk - 384) * 256 + tid;
    if (blk >= 384 && blk <= 388 && gid >= 0 && gid < 1176) {
        const int cum[5]  = {0,448,768,960,1176};
        const int cin[4]  = {32,64,64,64};
        const int kk[4]   = {7,5,3,3};
        const int wpp[4]  = {1,2,2,2};
        const int woff[4] = {356,804,1444,1828};
        const float* wsrc[4] = {a.W[3],a.W[4],a.W[5],a.W[6]};
        int L = 0;
        while (L < 3 && gid >= cum[L + 1]) ++L;
        const int idx = gid - cum[L];
        const int K = kk[L], CIN = cin[L], WPP = wpp[L];
        const int o = idx / K, k = idx - o * K;
        const float* w = wsrc[L];
        uint32_t m0 = 0, m1 = 0;
        for (int c = 0; c < CIN; ++c) {
            const float v = w[((size_t)o * CIN + c) * K + k];
            const uint32_t bit = (v < 0.f) ? 1u : 0u;
            int bp = c;
            if (CIN == 64) bp = 16 * (c & 3) + (c >> 2);
            else if (CIN == 32) bp = 8 * (c & 3) + (c >> 2);
            if (bp < 32) m0 |= bit << bp; else m1 |= bit << (bp - 32);
        }
        uint32_t* dst = a.wmb + woff[L] + (size_t)idx * WPP;
        dst[0] = m0;
        if (WPP == 2) dst[1] = m1;
    }

    if (blk == 389 && tid < 12) {   // bin2: byte-packed, 4 taps/word
        const float* w = a.W[1];    // (12,8,12)
        const int o = tid;
        #pragma unroll
        for (int g = 0; g < 3; ++g) {
            uint32_t word = 0;
            #pragma unroll
            for (int j = 0; j < 4; ++j) {
                const int k = 4 * g + j;
                uint32_t by = 0;
                #pragma unroll
                for (int c = 0; c < 8; ++c)
                    by |= (w[((size_t)o * 8 + c) * 12 + k] < 0.f ? 1u : 0u) << c;
                word |= by << (8 * j);
            }
            a.wmb[o * 3 + g] = word;
        }
    }
    if (blk == 390 && tid < 64) {   // bin3: u16-pair packed, even/odd phase
        const float* w = a.W[2];    // (32,12,9)
        const int o = tid >> 1, ph = tid & 1;
        uint32_t mk[9];
        #pragma unroll
        for (int k = 0; k < 9; ++k) {
            uint32_t m = 0;
            #pragma unroll
            for (int c = 0; c < 12; ++c)
                m |= (w[((size_t)o * 12 + c) * 9 + k] < 0.f ? 1u : 0u) << c;
            mk[k] = m;
        }
        uint32_t wd[5];
        if (ph == 0) { wd[0]=mk[0]|(mk[1]<<16); wd[1]=mk[2]|(mk[3]<<16);
                       wd[2]=mk[4]|(mk[5]<<16); wd[3]=mk[6]|(mk[7]<<16); wd[4]=mk[8]; }
        else         { wd[0]=mk[0]<<16; wd[1]=mk[1]|(mk[2]<<16);
                       wd[2]=mk[3]|(mk[4]<<16); wd[3]=mk[5]|(mk[6]<<16); wd[4]=mk[7]|(mk[8]<<16); }
        #pragma unroll
        for (int g = 0; g < 5; ++g) a.wmb[36 + o * 10 + ph * 5 + g] = wd[g];
    }
}

// ---------------- layer 1: register-resident conv, K=16, stride 2 -----------
// __launch_bounds__(256, 4): the kernel needs ~90 live VGPRs (f[40]+acc[12]+
// m0/m1[16]); with the default 8-wave occupancy target the allocator capped
// at ~64 VGPR and SPILLED TO SCRATCH inside the 1536-FMA hot loop (f[] comes
// from guarded global loads -> not rematerializable). Rebuilt budget model
// (R3/R7/R9 anchors): conv1-original = ~34 us vs ~14 us FMA-issue floor.
// min 4 waves/EU raises the cap to 128 VGPR; 16 waves/CU is ample TLP.
__global__ __launch_bounds__(256, 4) void k_conv1(Args a) {
    __shared__ float wgs[128];
    __shared__ double sred[16];
    const int n = blockIdx.x, tid = threadIdx.x, l = tid & 63;
    if (tid < 128) wgs[tid] = signf(a.W[0][tid]);
    if (tid < 16)  sred[tid] = 0.0;
    __syncthreads();
    const int r = tid;
    const float* xn = a.x + (size_t)n * 3600;
    float m0[8], m1[8];
    #pragma unroll
    for (int ch = 0; ch < 8; ++ch) { m0[ch] = 0.f; m1[ch] = 0.f; }
    if (r < 225) {
        float f[40];   // f[i] = x[16r-8+i]; taps f[2j+1+k] for p=8r+j
        const int g0 = 16 * r - 8;
        #pragma unroll
        for (int b = 0; b < 10; ++b) {
            const int gg = g0 + 4 * b;
            if (gg >= 0 && gg <= 3596) {
                const float4 v = *(const float4*)(xn + gg);
                f[4*b] = v.x; f[4*b+1] = v.y; f[4*b+2] = v.z; f[4*b+3] = v.w;
            } else {
                f[4*b] = 0.f; f[4*b+1] = 0.f; f[4*b+2] = 0.f; f[4*b+3] = 0.f;
            }
        }
        #pragma unroll
        for (int ch = 0; ch < 8; ++ch) {
            float acc[12];
            #pragma unroll
            for (int j = 0; j < 12; ++j) acc[j] = 0.f;
            #pragma unroll
            for (int k = 0; k < 16; ++k) {
                const float wk = wgs[ch * 16 + k];
                #pragma unroll
                for (int j = 0; j < 12; ++j)
                    acc[j] = fmaf(f[2*j + 1 + k], wk, acc[j]);
            }
            const float lo  = fmaxf(fmaxf(acc[0], acc[1]), fmaxf(acc[2], acc[3]));
            const float mid = fmaxf(fmaxf(acc[4], acc[5]), fmaxf(acc[6], acc[7]));
            const float hi  = fmaxf(fmaxf(acc[8], acc[9]), fmaxf(acc[10], acc[11]));
            const float sc = a.wsc[ch];
            m0[ch] = fmaxf(lo, mid) * sc;
            m1[ch] = (r < 224) ? fmaxf(mid, hi) * sc : 0.f;
        }
        float* on = a.bufA + ((size_t)n * 449 + 2 * r) * 8;
        *(float4*)(on + 0) = make_float4(m0[0], m0[1], m0[2], m0[3]);
        *(float4*)(on + 4) = make_float4(m0[4], m0[5], m0[6], m0[7]);
        if (r < 224) {
            *(float4*)(on + 8)  = make_float4(m1[0], m1[1], m1[2], m1[3]);
            *(float4*)(on + 12) = make_float4(m1[4], m1[5], m1[6], m1[7]);
        }
    }
    #pragma unroll
    for (int ch = 0; ch < 8; ++ch) {
        double sS = (double)m0[ch] + (double)m1[ch];
        double s2 = (double)m0[ch] * m0[ch] + (double)m1[ch] * m1[ch];
        #pragma unroll
        for (int off = 32; off; off >>= 1) {
            sS += __shfl_down(sS, off);
            s2 += __shfl_down(s2, off);
        }
        if (l == 0) {
            atomicAdd(&sred[ch], sS);
            atomicAdd(&sred[8 + ch], s2);
        }
    }
    __syncthreads();
    if (tid < 16) {
        double* so = a.stats + (size_t)(n & (NSLOT - 1)) * 16;
        atomicAdd(&so[tid], sred[tid]);
    }
}

// ---------------- layers 2..7 (compile-time spans + unrolled pack) ----------
// gridDim.y == 1 for every launch => q0=0, q1=LIN are COMPILE-TIME. Pack loops
// are #pragma-unroll MAXIT predicated loops so the compiler can batch all
// global loads ahead of the ballot chain (verified: bins+fc ~112 -> ~100 us
// with this structure, per rebuilt budget model).
template <int CIN, int LIN, int O, int K, int STRIDE, int PAD,
          int PK, int PS, int LP, int WPP, int LPB, int NS, bool SF64>
__device__ __forceinline__ void bin_body(
    const float* __restrict__ xprev, const uint32_t* __restrict__ wm,
    const float* __restrict__ wsc, const float* __restrict__ wsc_prev,
    const double* __restrict__ stats_in,
    const float* __restrict__ gamma, const float* __restrict__ beta,
    const double cntInv, float* __restrict__ out, double* __restrict__ stats_out)
{
    constexpr int OL    = (O < 64) ? O : 64;
    constexpr int PO    = 64 / OL;
    constexpr int WPW   = 4 / NS;       // waves per sample
    constexpr int SPAN  = (PK - 1) * STRIDE + K;
    constexpr int QLEN  = WPW * LPB * PS * STRIDE + SPAN;
    constexpr int XM64A =
        (WPP == 2)   ? (QLEN + 3)
      : (CIN == 8)   ? ((QLEN + 48) + 7) / 8          // byte layout
      : (CIN == 12)  ? ((2 * (QLEN + 10)) + 7) / 8    // u16 layout
      : ((QLEN + 5) / 2 + 2);                         // u32 layout (CIN=32)
    constexpr int F     = 2 * CIN;
    constexpr int FW    = (F > 64) ? 128 : 64;
    constexpr int XBASE = (CIN == 8 || CIN == 12) ? 0
                        : (WPP == 1) ? -(PAD & 1) : 0;   // keeps (lo-XBASE) parity

    __shared__ uint64_t xmbuf[NS][XM64A];
    __shared__ long long foldU[4][FW];
    __shared__ int sS[4][O], sS2[4][O];

    const int tid  = threadIdx.x;
    const int wv   = tid >> 6;
    const int l    = tid & 63;
    const int sloc = wv / WPW;          // sample slot within block
    const int wvs  = wv % WPW;          // wave index within sample
    uint64_t* xm64 = xmbuf[sloc];
    uint32_t* xm32 = (uint32_t*)xm64;
    uint16_t* xm16 = (uint16_t*)xm64;
    uint8_t*  xm8  = (uint8_t*)xm64;

    const int n   = blockIdx.x * NS + sloc;
    const int lp0 = wvs * LPB;
    const int lp1 = (lp0 + LPB < LP) ? lp0 + LPB : LP;

    const float* xn = xprev + (size_t)n * LIN * CIN;

    // ---- BN fold (batch-constant): once per block, 4 waves co-op ----
    {
        const long long* stI = (const long long*)stats_in;
        long long pa = 0, pb_ = 0;
        double da = 0.0;
        #pragma unroll
        for (int s8 = 0; s8 < 8; ++s8) {
            const int s = (wv << 3) + s8;
            if constexpr (SF64) {
                if (l < F) da += stats_in[s * F + l];
            } else {
                if (l < ((F < 64) ? F : 64)) pa += stI[s * F + l];
                if constexpr (F > 64) { if (l < F - 64) pb_ += stI[s * F + 64 + l]; }
            }
        }
        if constexpr (SF64) foldU[wv][l] = __double_as_longlong(da);
        else {
            foldU[wv][l] = pa;
            if constexpr (F > 64) foldU[wv][64 + l] = pb_;
        }
    }
    __syncthreads();
    float aA = 0.f, aB = 0.f;
    {
        double t0 = 0.0, t1 = 0.0;
        if constexpr (SF64) {
            double tot = 0.0;
            #pragma unroll
            for (int w = 0; w < 4; ++w) tot += __longlong_as_double(foldU[w][l]);
            t0 = tot;
            t1 = __shfl(tot, CIN + l);
        } else if constexpr (F > 64) {
            long long a0 = 0, a1 = 0;
            #pragma unroll
            for (int w = 0; w < 4; ++w) { a0 += foldU[w][l]; a1 += foldU[w][64 + l]; }
            t0 = (double)a0; t1 = (double)a1;
        } else {
            long long a0 = 0;
            #pragma unroll
            for (int w = 0; w < 4; ++w) a0 += foldU[w][l];
            const double tot = (double)a0;
            t0 = tot;
            t1 = __shfl(tot, CIN + l);
        }
        if (l < CIN) {
            double mean, E2;
            if constexpr (SF64) { mean = t0 * cntInv; E2 = t1 * cntInv; }
            else {
                const double w = (double)wsc_prev[l];
                mean = w * t0 * cntInv; E2 = w * w * t1 * cntInv;
            }
            const double var = E2 - mean * mean;
            const double inv = 1.0 / sqrt(var + 1e-5);
            const double av  = (double)gamma[l] * inv;
            aA = (float)av;
            aB = (float)((double)beta[l] - mean * av);
        }
    }

    // ---- pack [0, LIN), WPW waves interleaved, fully unrolled ----
    if constexpr (CIN == 64) {
        constexpr int STP = WPW * 4;
        constexpr int MAXIT = (LIN + STP - 1) / STP;
        const int sub = l & 15, grp = l >> 4;
        const float a0 = __shfl(aA, 4*sub),     b0 = __shfl(aB, 4*sub);
        const float a1 = __shfl(aA, 4*sub + 1), b1 = __shfl(aB, 4*sub + 1);
        const float a2 = __shfl(aA, 4*sub + 2), b2 = __shfl(aB, 4*sub + 2);
        const float a3 = __shfl(aA, 4*sub + 3), b3 = __shfl(aB, 4*sub + 3);
        #pragma unroll
        for (int it = 0; it < MAXIT; ++it) {
            const int pb = wvs * 4 + it * STP;
            const int pos = pb + grp;
            const bool valid = pos < LIN;
            const float4 v = *(const float4*)(xn + (size_t)(valid ? pos : 0) * 64 + 4*sub);
            const unsigned long long bal0 = __ballot(valid && (fmaf(a0, v.x, b0) < 0.f));
            const unsigned long long bal1 = __ballot(valid && (fmaf(a1, v.y, b1) < 0.f));
            const unsigned long long bal2 = __ballot(valid && (fmaf(a2, v.z, b2) < 0.f));
            const unsigned long long bal3 = __ballot(valid && (fmaf(a3, v.w, b3) < 0.f));
            if (l < 4 && pb + l < LIN) {
                const uint64_t m = ((bal0 >> (16*l)) & 0xFFFFull)
                                 | (((bal1 >> (16*l)) & 0xFFFFull) << 16)
                                 | (((bal2 >> (16*l)) & 0xFFFFull) << 32)
                                 | (((bal3 >> (16*l)) & 0xFFFFull) << 48);
                xm64[pb + l - XBASE] = m;
            }
        }
    } else if constexpr (CIN == 32) {
        constexpr int STP = WPW * 8;
        constexpr int MAXIT = (LIN + STP - 1) / STP;
        const int sub = l & 7, grp = l >> 3;
        const float a0 = __shfl(aA, 4*sub),     b0 = __shfl(aB, 4*sub);
        const float a1 = __shfl(aA, 4*sub + 1), b1 = __shfl(aB, 4*sub + 1);
        const float a2 = __shfl(aA, 4*sub + 2), b2 = __shfl(aB, 4*sub + 2);
        const float a3 = __shfl(aA, 4*sub + 3), b3 = __shfl(aB, 4*sub + 3);
        #pragma unroll
        for (int it = 0; it < MAXIT; ++it) {
            const int pb = wvs * 8 + it * STP;
            const int pos = pb + grp;
            const bool valid = pos < LIN;
            const float4 v = *(const float4*)(xn + (size_t)(valid ? pos : 0) * 32 + 4*sub);
            const unsigned long long bal0 = __ballot(valid && (fmaf(a0, v.x, b0) < 0.f));
            const unsigned long long bal1 = __ballot(valid && (fmaf(a1, v.y, b1) < 0.f));
            const unsigned long long bal2 = __ballot(valid && (fmaf(a2, v.z, b2) < 0.f));
            const unsigned long long bal3 = __ballot(valid && (fmaf(a3, v.w, b3) < 0.f));
            if (l < 8 && pb + l < LIN) {
                const uint32_t m = (uint32_t)((bal0 >> (8*l)) & 0xFFull)
                                 | ((uint32_t)((bal1 >> (8*l)) & 0xFFull) << 8)
                                 | ((uint32_t)((bal2 >> (8*l)) & 0xFFull) << 16)
                                 | ((uint32_t)((bal3 >> (8*l)) & 0xFFull) << 24);
                xm32[pb + l - XBASE] = m;
            }
        }
    } else if constexpr (CIN == 8) {
        constexpr int STP = WPW * 32;
        constexpr int MAXIT = (LIN + STP - 1) / STP;
        const int sub = l & 1, grp = l >> 1;
        const float a0 = __shfl(aA, 4*sub),     b0 = __shfl(aB, 4*sub);
        const float a1 = __shfl(aA, 4*sub + 1), b1 = __shfl(aB, 4*sub + 1);
        const float a2 = __shfl(aA, 4*sub + 2), b2 = __shfl(aB, 4*sub + 2);
        const float a3 = __shfl(aA, 4*sub + 3), b3 = __shfl(aB, 4*sub + 3);
        #pragma unroll
        for (int it = 0; it < MAXIT; ++it) {
            const int pb = wvs * 32 + it * STP;
            const int pos = pb + grp;
            const bool valid = pos < LIN;
            const float4 v = *(const float4*)(xn + (size_t)(valid ? pos : 0) * 8 + 4*sub);
            const unsigned long long bal0 = __ballot(valid && (fmaf(a0, v.x, b0) < 0.f));
            const unsigned long long bal1 = __ballot(valid && (fmaf(a1, v.y, b1) < 0.f));
            const unsigned long long bal2 = __ballot(valid && (fmaf(a2, v.z, b2) < 0.f));
            const unsigned long long bal3 = __ballot(valid && (fmaf(a3, v.w, b3) < 0.f));
            if (l < 32 && pb + l < LIN) {
                const uint32_t t0 = (uint32_t)((bal0 >> (2*l)) & 3ull);
                const uint32_t t1 = (uint32_t)((bal1 >> (2*l)) & 3ull);
                const uint32_t t2 = (uint32_t)((bal2 >> (2*l)) & 3ull);
                const uint32_t t3 = (uint32_t)((bal3 >> (2*l)) & 3ull);
                const uint32_t m = (t0 & 1) | ((t1 & 1) << 1) | ((t2 & 1) << 2) | ((t3 & 1) << 3)
                                 | ((t0 >> 1) << 4) | ((t1 >> 1) << 5) | ((t2 >> 1) << 6) | ((t3 >> 1) << 7);
                xm8[pb + l - XBASE] = (uint8_t)m;     // BYTE layout
            }
        }
    } else {   // CIN == 12 -> u16 layout
        constexpr int PPW = 64 / CIN;
        constexpr int STP = WPW * PPW;
        constexpr int MAXIT = (LIN + STP - 1) / STP;
        const int pw = l / CIN, c = l - pw * CIN;
        const float myA = __shfl(aA, c), myB = __shfl(aB, c);
        const bool lact = (pw < PPW);
        #pragma unroll
        for (int it = 0; it < MAXIT; ++it) {
            const int pb = wvs * PPW + it * STP;
            const int pos = pb + pw;
            const bool act = lact && (pos < LIN) && (pb < LIN);
            float v = 0.f;
            if (act) v = fmaf(myA, xn[(size_t)pb * CIN + l], myB);
            const unsigned long long bal = __ballot(act && (v < 0.f));
            if (act && c == 0) {
                const uint32_t mk = (uint32_t)((bal >> (pw * CIN)) & ((1u << CIN) - 1));
                xm16[pos - XBASE] = (uint16_t)mk;
            }
        }
    }
    __syncthreads();

    // ---- conv + pool + integer stats over this wave's [lp0, lp1) ----
    float* on = out + (size_t)n * LP * O;

    if constexpr (WPP == 2) {
        const uint64_t* wmp = (const uint64_t*)wm;
        uint64_t wr[K];
        #pragma unroll
        for (int k = 0; k < K; ++k) wr[k] = wmp[l * K + k];
        uint64_t wr2[K];
        const int oo2 = 64 + ((O > 64 && l < O - 64) ? l : 0);
        if constexpr (O > 64) {
            #pragma unroll
            for (int k = 0; k < K; ++k) wr2[k] = wmp[oo2 * K + k];
        }
        const float myws  = wsc[l];
        const float myws2 = (O > 64 && l < O - 64) ? wsc[64 + l] : 0.f;
        int accS = 0, accS2 = 0, accSb = 0, accS2b = 0;

        #pragma unroll
        for (int li = 0; li < LPB; ++li) {
            const int lp = lp0 + li;
            if (lp < lp1) {
                const int lo = lp * PS * STRIDE - PAD;
                int m = -1000000, m2 = -1000000;
                if (lo >= 0 && lo + SPAN <= LIN) {
                    uint64_t tw[SPAN];
                    #pragma unroll
                    for (int t = 0; t < SPAN; ++t) tw[t] = xm64[lo - XBASE + t];
                    #pragma unroll
                    for (int j = 0; j < PK; ++j) {
                        int p = 0;
                        #pragma unroll
                        for (int k = 0; k < K; ++k)
                            p += __popcll(tw[j * STRIDE + k] ^ wr[k]);
                        m = max(m, CIN * K - 2 * p);
                        if constexpr (O > 64) {
                            int p2 = 0;
                            #pragma unroll
                            for (int k = 0; k < K; ++k)
                                p2 += __popcll(tw[j * STRIDE + k] ^ wr2[k]);
                            m2 = max(m2, CIN * K - 2 * p2);
                        }
                    }
                } else {
                    #pragma unroll
                    for (int j = 0; j < PK; ++j) {
                        const int base = lo + j * STRIDE;
                        int p = 0, nv = 0, p2 = 0;
                        #pragma unroll
                        for (int k = 0; k < K; ++k) {
                            const int q = base + k;
                            if (q >= 0 && q < LIN) {
                                ++nv;
                                const uint64_t xv = xm64[q - XBASE];
                                p += __popcll(xv ^ wr[k]);
                                if constexpr (O > 64) p2 += __popcll(xv ^ wr2[k]);
                            }
                        }
                        m = max(m, CIN * nv - 2 * p);
                        if constexpr (O > 64) m2 = max(m2, CIN * nv - 2 * p2);
                    }
                }
                on[lp * O + l] = (float)m * myws;
                accS += m; accS2 += m * m;
                if constexpr (O > 64) {
                    if (l < O - 64) {
                        on[lp * O + 64 + l] = (float)m2 * myws2;
                        accSb += m2; accS2b += m2 * m2;
                    }
                }
            }
        }
        sS[wv][l] = accS; sS2[wv][l] = accS2;
        if constexpr (O > 64) {
            if (l < O - 64) { sS[wv][64 + l] = accSb; sS2[wv][64 + l] = accS2b; }
        }
    } else if constexpr (CIN == 8) {
        // bin2: byte layout, 3 popc32 per window (K=12, PK=4, STRIDE=2)
        const int po = l / OL, oo = l - po * OL;     // OL=12, PO=5
        const bool cact = (po < PO);
        const float myws = cact ? wsc[oo] : 0.f;
        const int osel = cact ? oo : 0;
        const uint32_t wr0 = wm[osel*3], wr1 = wm[osel*3+1], wr2 = wm[osel*3+2];
        uint32_t wb[12];
        #pragma unroll
        for (int k = 0; k < 12; ++k)
            wb[k] = ((k < 4 ? wr0 : (k < 8 ? wr1 : wr2)) >> (8 * (k & 3))) & 255u;
        const uint32_t* xw = (const uint32_t*)xm64;
        int accS = 0, accS2 = 0;

        #pragma unroll 2
        for (int lp = lp0 + po; lp < lp1; lp += PO) {
            const int lo = lp * PS * STRIDE - PAD;   // = 4lp-5, ≡3 mod 4
            int m = -1000000;
            if (lo >= 0 && lo + SPAN <= LIN) {
                const int bb = lo - XBASE;           // ≡3 mod 4
                const int w0 = bb >> 2;
                uint32_t tw[6];
                #pragma unroll
                for (int i = 0; i < 6; ++i) tw[i] = xw[w0 + i];
                #pragma unroll
                for (int j = 0; j < PK; ++j) {
                    const int wo = (j + 1) >> 1;     // 0,1,1,2
                    uint32_t e0, e1, e2;
                    if (j & 1) {                     // shift 8
                        e0 = (tw[wo]   >> 8) | (tw[wo+1] << 24);
                        e1 = (tw[wo+1] >> 8) | (tw[wo+2] << 24);
                        e2 = (tw[wo+2] >> 8) | (tw[wo+3] << 24);
                    } else {                         // shift 24
                        e0 = (tw[wo]   >> 24) | (tw[wo+1] << 8);
                        e1 = (tw[wo+1] >> 24) | (tw[wo+2] << 8);
                        e2 = (tw[wo+2] >> 24) | (tw[wo+3] << 8);
                    }
                    const int p = __popc(e0 ^ wr0) + __popc(e1 ^ wr1) + __popc(e2 ^ wr2);
                    m = max(m, 96 - 2 * p);
                }
            } else {
                #pragma unroll
                for (int j = 0; j < PK; ++j) {
                    const int base = lo + j * STRIDE;
                    int p = 0, nv = 0;
                    #pragma unroll
                    for (int k = 0; k < 12; ++k) {
                        const int q = base + k;
                        if (q >= 0 && q < LIN) { ++nv; p += __popc((uint32_t)xm8[q - XBASE] ^ wb[k]); }
                    }
                    m = max(m, 8 * nv - 2 * p);
                }
            }
            if (cact) {
                on[lp * O + oo] = (float)m * myws;
                accS += m; accS2 += m * m;
            }
        }
        int t = accS, t2 = accS2;
        #pragma unroll
        for (int g = 1; g < PO; ++g) {
            t  += __shfl(accS,  l + g * OL);
            t2 += __shfl(accS2, l + g * OL);
        }
        if (l < OL) { sS[wv][l] = t; sS2[wv][l] = t2; }
        else if (l < O) { sS[wv][l] = 0; sS2[wv][l] = 0; }
    } else if constexpr (CIN == 12) {
        // bin3: u16 layout, 5 popc32 per window (K=9, PK=5, STRIDE=1)
        const int po = l / OL, oo = l - po * OL;     // OL=32, PO=2
        const bool cact = (po < PO);
        const float myws = cact ? wsc[oo] : 0.f;
        const int osel = cact ? oo : 0;
        uint32_t wE[5], wO[5];
        #pragma unroll
        for (int g = 0; g < 5; ++g) { wE[g] = wm[osel*10 + g]; wO[g] = wm[osel*10 + 5 + g]; }
        uint32_t we16[9];
        we16[0]=wE[0]&0xFFFFu; we16[1]=wE[0]>>16; we16[2]=wE[1]&0xFFFFu; we16[3]=wE[1]>>16;
        we16[4]=wE[2]&0xFFFFu; we16[5]=wE[2]>>16; we16[6]=wE[3]&0xFFFFu; we16[7]=wE[3]>>16;
        we16[8]=wE[4]&0xFFFFu;
        const uint32_t* xw = (const uint32_t*)xm64;
        int accS = 0, accS2 = 0;

        #pragma unroll 2
        for (int lp = lp0 + po; lp < lp1; lp += PO) {
            const int lo = lp * PS * STRIDE - PAD;   // = 2lp-4, even
            int m = -1000000;
            if (lo >= 0 && lo + SPAN <= LIN) {
                const int s0 = (lo - XBASE) >> 1;    // (lo-XBASE) even
                uint32_t tw[7];
                #pragma unroll
                for (int i = 0; i < 7; ++i) tw[i] = xw[s0 + i];
                #pragma unroll
                for (int j = 0; j < PK; ++j) {
                    const int o_ = j >> 1;
                    int p;
                    if (j & 1)
                        p = __popc((tw[o_] & 0xFFFF0000u) ^ wO[0]) + __popc(tw[o_+1] ^ wO[1])
                          + __popc(tw[o_+2] ^ wO[2]) + __popc(tw[o_+3] ^ wO[3])
                          + __popc(tw[o_+4] ^ wO[4]);
                    else
                        p = __popc(tw[o_] ^ wE[0]) + __popc(tw[o_+1] ^ wE[1])
                          + __popc(tw[o_+2] ^ wE[2]) + __popc(tw[o_+3] ^ wE[3])
                          + __popc((tw[o_+4] & 0xFFFFu) ^ wE[4]);
                    m = max(m, 108 - 2 * p);
                }
            } else {
                #pragma unroll
                for (int j = 0; j < PK; ++j) {
                    const int base = lo + j * STRIDE;
                    int p = 0, nv = 0;
                    #pragma unroll
                    for (int k = 0; k < 9; ++k) {
                        const int q = base + k;
                        if (q >= 0 && q < LIN) { ++nv; p += __popc((uint32_t)xm16[q - XBASE] ^ we16[k]); }
                    }
                    m = max(m, 12 * nv - 2 * p);
                }
            }
            if (cact) {
                on[lp * O + oo] = (float)m * myws;
                accS += m; accS2 += m * m;
            }
        }
        int t = accS, t2 = accS2;
        #pragma unroll
        for (int g = 1; g < PO; ++g) {
            t  += __shfl(accS,  l + g * OL);
            t2 += __shfl(accS2, l + g * OL);
        }
        if (l < OL) { sS[wv][l] = t; sS2[wv][l] = t2; }
    } else {
        // bin4 (CIN=32, O=64, PO=1): u32-mask path
        const int po = l / OL, oo = l - po * OL;
        const bool cact = (po < PO);
        const float myws = cact ? wsc[oo] : 0.f;
        uint32_t wr[K];
        #pragma unroll
        for (int k = 0; k < K; ++k) wr[k] = wm[(cact ? oo : 0) * K + k];
        int accS = 0, accS2 = 0;

        constexpr int PAIRS = (SPAN + 1) / 2;
        #pragma unroll 2
        for (int lp = lp0 + po; lp < lp1; lp += PO) {
            const int lo = lp * PS * STRIDE - PAD;   // (lo - XBASE) even
            int m = -1000000;
            if (lo >= 0 && lo + SPAN <= LIN) {
                uint32_t tw[PAIRS * 2];
                const int e0 = (lo - XBASE) >> 1;
                #pragma unroll
                for (int i = 0; i < PAIRS; ++i) {
                    const uint64_t u64v = xm64[e0 + i];
                    tw[2 * i]     = (uint32_t)u64v;
                    tw[2 * i + 1] = (uint32_t)(u64v >> 32);
                }
                #pragma unroll
                for (int j = 0; j < PK; ++j) {
                    int p = 0;
                    #pragma unroll
                    for (int k = 0; k < K; ++k)
                        p += __popc(tw[j * STRIDE + k] ^ wr[k]);
                    m = max(m, CIN * K - 2 * p);
                }
            } else {
                #pragma unroll
                for (int j = 0; j < PK; ++j) {
                    const int base = lo + j * STRIDE;
                    int p = 0, nv = 0;
                    #pragma unroll
                    for (int k = 0; k < K; ++k) {
                        const int q = base + k;
                        if (q >= 0 && q < LIN) { ++nv; p += __popc(xm32[q - XBASE] ^ wr[k]); }
                    }
                    m = max(m, CIN * nv - 2 * p);
                }
            }
            if (cact) {
                on[lp * O + oo] = (float)m * myws;
                accS += m; accS2 += m * m;
            }
        }
        int t = accS, t2 = accS2;
        #pragma unroll
        for (int g = 1; g < PO; ++g) {
            t  += __shfl(accS,  l + g * OL);
            t2 += __shfl(accS2, l + g * OL);
        }
        if (l < OL) { sS[wv][l] = t; sS2[wv][l] = t2; }
    }
    __syncthreads();

    // ---- one int64 atomic set per block (slot choice free: fold sums all) --
    const int slot = ((NS == 1) ? n : (int)blockIdx.x) & (NSLOT - 1);
    unsigned long long* soU =
        (unsigned long long*)stats_out + (size_t)slot * 2 * O;
    for (int t = tid; t < 2 * O; t += 256) {
        int tot;
        if (t < O) tot = sS[0][t] + sS[1][t] + sS[2][t] + sS[3][t];
        else { const int f = t - O; tot = sS2[0][f] + sS2[1][f] + sS2[2][f] + sS2[3][f]; }
        atomicAdd(&soU[t], (unsigned long long)(long long)tot);
    }
}

#define BIN_PARAMS \
    const float* __restrict__ xprev, const uint32_t* __restrict__ wm, \
    const float* __restrict__ wsc, const float* __restrict__ wsc_prev, \
    const double* __restrict__ stats_in, \
    const float* __restrict__ gamma, const float* __restrict__ beta, \
    const double cntInv, float* __restrict__ out, double* __restrict__ stats_out
#define BIN_ARGS xprev, wm, wsc, wsc_prev, stats_in, gamma, beta, cntInv, out, stats_out

__global__ __launch_bounds__(256) void k_bin2(BIN_PARAMS) { bin_body< 8,449,12,12,2,5,4,2,111,1,28,1,true >(BIN_ARGS); }
__global__ __launch_bounds__(256) void k_bin3(BIN_PARAMS) { bin_body<12,111,32, 9,1,4,5,2, 54,1,14,1,false>(BIN_ARGS); }
__global__ __launch_bounds__(256) void k_bin4(BIN_PARAMS) { bin_body<32, 54,64, 7,1,3,4,2, 26,1, 7,1,false>(BIN_ARGS); }
__global__ __launch_bounds__(256) void k_bin5(BIN_PARAMS) { bin_body<64, 26,64, 5,1,2,2,2, 13,2, 7,2,false>(BIN_ARGS); }
__global__ __launch_bounds__(256) void k_bin6(BIN_PARAMS) { bin_body<64, 13,64, 3,1,1,2,2,  6,2, 3,2,false>(BIN_ARGS); }
__global__ __launch_bounds__(256) void k_bin7(BIN_PARAMS) { bin_body<64,  6,72, 3,1,1,2,2,  3,2, 2,2,false>(BIN_ARGS); }

// ---------------- FC, wave-per-sample, 4 samples per block ------------------
__global__ __launch_bounds__(256) void k_fc(Args a) {
    const int n = blockIdx.x * 4 + (int)(threadIdx.x >> 6);
    const int l = (int)(threadIdx.x & 63);
    const long long* st = (const long long*)(a.stats + 15616);
    long long s = 0, s2 = 0, sb = 0, s2b = 0;
    #pragma unroll 4
    for (int sl = 0; sl < NSLOT; ++sl) {
        s  += st[sl * 144 + l];
        s2 += st[sl * 144 + 72 + l];
        if (l < 8) {
            sb  += st[sl * 144 + 64 + l];
            s2b += st[sl * 144 + 72 + 64 + l];
        }
    }
    float aA0, aB0, aA1 = 0.f, aB1 = 0.f;
    {
        const double w = (double)a.wsc[244 + l];
        const double mean = w * (double)s / 6144.0;
        const double E2   = w * w * (double)s2 / 6144.0;
        const double var  = E2 - mean * mean;
        const double inv  = 1.0 / sqrt(var + 1e-5);
        const double aa   = (double)a.G[6][l] * inv;
        aA0 = (float)aa; aB0 = (float)((double)a.Bt[6][l] - mean * aa);
    }
    if (l < 8) {
        const double w = (double)a.wsc[244 + 64 + l];
        const double mean = w * (double)sb / 6144.0;
        const double E2   = w * w * (double)s2b / 6144.0;
        const double var  = E2 - mean * mean;
        const double inv  = 1.0 / sqrt(var + 1e-5);
        const double aa   = (double)a.G[6][64 + l] * inv;
        aA1 = (float)aa; aB1 = (float)((double)a.Bt[6][64 + l] - mean * aa);
    }
    const float* p7 = a.bufA + (size_t)n * 216;
    float acc[5] = {0.f, 0.f, 0.f, 0.f, 0.f};
    #pragma unroll
    for (int j = 0; j < 4; ++j) {
        const int i = l + 64 * j;
        const int ic = (i < 216) ? i : 215;
        const int c = ic / 3, lp = ic - 3 * c;       // flatten is [72,3]
        float aa = __shfl(aA0, c);
        float bb = __shfl(aB0, c);
        const float aaH = __shfl(aA1, c - 64);
        const float bbH = __shfl(aB1, c - 64);
        if (c >= 64) { aa = aaH; bb = bbH; }
        if (i < 216) {
            const float av = signf(fmaf(aa, p7[lp * 72 + c], bb));
            #pragma unroll
            for (int o = 0; o < 5; ++o)
                acc[o] += av * signf(a.WFC[o * 216 + i]);
        }
    }
    #pragma unroll
    for (int o = 0; o < 5; ++o) {
        float v = acc[o];
        #pragma unroll
        for (int off = 32; off; off >>= 1) v += __shfl_down(v, off);
        if (l == 0) a.out[(size_t)n * 5 + o] = v * a.wsc[316 + o];
    }
}

extern "C" void kernel_launch(void* const* d_in, const int* in_sizes, int n_in,
                              void* d_out, int out_size, void* d_ws, size_t ws_size,
                              hipStream_t stream) {
    Args a;
    a.x = (const float*)d_in[0];
    for (int i = 0; i < 7; ++i) {
        a.W[i]  = (const float*)d_in[1 + 3 * i];
        a.G[i]  = (const float*)d_in[2 + 3 * i];
        a.Bt[i] = (const float*)d_in[3 + 3 * i];
    }
    a.WFC = (const float*)d_in[22];
    a.out = (float*)d_out;

    char* ws = (char*)d_ws;
    a.bufA  = (float*)ws;                       // 29,425,664 B
    a.bufB  = (float*)(ws + 29425664);          // 13,631,488 B
    a.stats = (double*)(ws + 43057152);         // 20224 slots
    a.wsc   = (float*)(ws + 43218944);          // 1284 B
    a.wmb   = (uint32_t*)d_out;                 // 9040 B, dead before fc writes

    k_setup<<<391, 256, 0, stream>>>(a);
    k_conv1<<<NBATCH, 256, 0, stream>>>(a);
    // stats (8B units): L1@0, L2@512, L3@1280, L4@3328, L5@7424, L6@11520, L7@15616
    k_bin2<<<dim3(NBATCH, 1), 256, 0, stream>>>(
        a.bufA, a.wmb + 0, a.wsc + 8, a.wsc, a.stats + 0, a.G[0], a.Bt[0],
        1.0/919552.0, a.bufB, a.stats + 512);
    k_bin3<<<dim3(NBATCH, 1), 256, 0, stream>>>(
        a.bufB, a.wmb + 36, a.wsc + 20, a.wsc + 8, a.stats + 512, a.G[1], a.Bt[1],
        1.0/227328.0, a.bufA, a.stats + 1280);
    k_bin4<<<dim3(NBATCH, 1), 256, 0, stream>>>(
        a.bufA, a.wmb + 356, a.wsc + 52, a.wsc + 20, a.stats + 1280, a.G[2], a.Bt[2],
        1.0/110592.0, a.bufB, a.stats + 3328);
    k_bin5<<<dim3(NBATCH / 2, 1), 256, 0, stream>>>(
        a.bufB, a.wmb + 804, a.wsc + 116, a.wsc + 52, a.stats + 3328, a.G[3], a.Bt[3],
        1.0/53248.0, a.bufA, a.stats + 7424);
    k_bin6<<<dim3(NBATCH / 2, 1), 256, 0, stream>>>(
        a.bufA, a.wmb + 1444, a.wsc + 180, a.wsc + 116, a.stats + 7424, a.G[4], a.Bt[4],
        1.0/26624.0, a.bufB, a.stats + 11520);
    k_bin7<<<dim3(NBATCH / 2, 1), 256, 0, stream>>>(
        a.bufB, a.wmb + 1828, a.wsc + 244, a.wsc + 180, a.stats + 11520, a.G[5], a.Bt[5],
        1.0/12288.0, a.bufA, a.stats + 15616);
    k_fc<<<NBATCH / 4, 256, 0, stream>>>(a);
}

// Round 12
// 246.808 us; speedup vs baseline: 1.0005x; 1.0005x over previous
//
#include <hip/hip_runtime.h>
#include <math.h>
#include <stdint.h>

#define NBATCH 2048
#define NSLOT 32

struct Args {
    const float* x;
    const float* W[7];
    const float* G[7];
    const float* Bt[7];
    const float* WFC;
    float* out;
    float* bufA;      // 29,425,664 B
    float* bufB;      // 13,631,488 B
    double* stats;    // 20224 8-byte slots (L1 region f64; L2..L7 regions int64)
    float* wsc;       // 321 floats
    uint32_t* wmb;    // 2260 words (lives in d_out, dead until fc)
};

__device__ __forceinline__ float signf(float v) {
    return (v > 0.f) ? 1.f : ((v < 0.f) ? -1.f : 0.f);
}

// ---------------- setup: zero stats, weight scales, weight bit-pack ---------
// wmb layout (words): bin2@0 (12x3 byte-packed), bin3@36 (32x{E,O}x5 u16-pair),
// bin4@356 (64x7), bin5@804 (64x5 u64), bin6@1444 (64x3 u64), bin7@1828 (72x3 u64).
// CIN=64: bit 16*(c&3)+(c>>2); CIN=32: bit 8*(c&3)+(c>>2); CIN<=12: bit c.
__global__ __launch_bounds__(256) void k_setup(Args a) {
    const int blk = blockIdx.x, tid = threadIdx.x;
    for (int i = blk * 256 + tid; i < NSLOT * 632; i += 391 * 256) a.stats[i] = 0.0;

    if (blk < 321 && tid < 64) {   // mean|w| per output channel
        const int cum[9] = {0,8,20,52,116,180,244,316,321};
        const int per[8] = {16,96,108,224,320,192,192,216};
        const float* wsrc[8] = {a.W[0],a.W[1],a.W[2],a.W[3],a.W[4],a.W[5],a.W[6],a.WFC};
        int o = blk, L = 0;
        while (L < 7 && o >= cum[L + 1]) ++L;
        const int oo = o - cum[L], p = per[L];
        const float* wo = wsrc[L] + (size_t)oo * p;
        float s = 0.f;
        for (int i = tid; i < p; i += 64) s += fabsf(wo[i]);
        #pragma unroll
        for (int off = 32; off; off >>= 1) s += __shfl_down(s, off);
        if (tid == 0) a.wsc[o] = s / (float)p;
    }

    // blocks 384..388: generic sign pack for bin4..bin7
    const int gid = (blk - 384) * 256 + tid;
    if (blk >= 384 && blk <= 388 && gid >= 0 && gid < 1176) {
        const int cum[5]  = {0,448,768,960,1176};
        const int cin[4]  = {32,64,64,64};
        const int kk[4]   = {7,5,3,3};
        const int wpp[4]  = {1,2,2,2};
        const int woff[4] = {356,804,1444,1828};
        const float* wsrc[4] = {a.W[3],a.W[4],a.W[5],a.W[6]};
        int L = 0;
        while (L < 3 && gid >= cum[L + 1]) ++L;
        const int idx = gid - cum[L];
        const int K = kk[L], CIN = cin[L], WPP = wpp[L];
        const int o = idx / K, k = idx - o * K;
        const float* w = wsrc[L];
        uint32_t m0 = 0, m1 = 0;
        for (int c = 0; c < CIN; ++c) {
            const float v = w[((size_t)o * CIN + c) * K + k];
            const uint32_t bit = (v < 0.f) ? 1u : 0u;
            int bp = c;
            if (CIN == 64) bp = 16 * (c & 3) + (c >> 2);
            else if (CIN == 32) bp = 8 * (c & 3) + (c >> 2);
            if (bp < 32) m0 |= bit << bp; else m1 |= bit << (bp - 32);
        }
        uint32_t* dst = a.wmb + woff[L] + (size_t)idx * WPP;
        dst[0] = m0;
        if (WPP == 2) dst[1] = m1;
    }

    if (blk == 389 && tid < 12) {   // bin2: byte-packed, 4 taps/word
        const float* w = a.W[1];    // (12,8,12)
        const int o = tid;
        #pragma unroll
        for (int g = 0; g < 3; ++g) {
            uint32_t word = 0;
            #pragma unroll
            for (int j = 0; j < 4; ++j) {
                const int k = 4 * g + j;
                uint32_t by = 0;
                #pragma unroll
                for (int c = 0; c < 8; ++c)
                    by |= (w[((size_t)o * 8 + c) * 12 + k] < 0.f ? 1u : 0u) << c;
                word |= by << (8 * j);
            }
            a.wmb[o * 3 + g] = word;
        }
    }
    if (blk == 390 && tid < 64) {   // bin3: u16-pair packed, even/odd phase
        const float* w = a.W[2];    // (32,12,9)
        const int o = tid >> 1, ph = tid & 1;
        uint32_t mk[9];
        #pragma unroll
        for (int k = 0; k < 9; ++k) {
            uint32_t m = 0;
            #pragma unroll
            for (int c = 0; c < 12; ++c)
                m |= (w[((size_t)o * 12 + c) * 9 + k] < 0.f ? 1u : 0u) << c;
            mk[k] = m;
        }
        uint32_t wd[5];
        if (ph == 0) { wd[0]=mk[0]|(mk[1]<<16); wd[1]=mk[2]|(mk[3]<<16);
                       wd[2]=mk[4]|(mk[5]<<16); wd[3]=mk[6]|(mk[7]<<16); wd[4]=mk[8]; }
        else         { wd[0]=mk[0]<<16; wd[1]=mk[1]|(mk[2]<<16);
                       wd[2]=mk[3]|(mk[4]<<16); wd[3]=mk[5]|(mk[6]<<16); wd[4]=mk[7]|(mk[8]<<16); }
        #pragma unroll
        for (int g = 0; g < 5; ++g) a.wmb[36 + o * 10 + ph * 5 + g] = wd[g];
    }
}

// ---------------- layer 1: register-resident conv, K=16, stride 2 -----------
__global__ __launch_bounds__(256) void k_conv1(Args a) {
    __shared__ float wgs[128];
    __shared__ double sred[16];
    const int n = blockIdx.x, tid = threadIdx.x, l = tid & 63;
    if (tid < 128) wgs[tid] = signf(a.W[0][tid]);
    if (tid < 16)  sred[tid] = 0.0;
    __syncthreads();
    const int r = tid;
    const float* xn = a.x + (size_t)n * 3600;
    float m0[8], m1[8];
    #pragma unroll
    for (int ch = 0; ch < 8; ++ch) { m0[ch] = 0.f; m1[ch] = 0.f; }
    if (r < 225) {
        float f[40];   // f[i] = x[16r-8+i]; taps f[2j+1+k] for p=8r+j
        const int g0 = 16 * r - 8;
        #pragma unroll
        for (int b = 0; b < 10; ++b) {
            const int gg = g0 + 4 * b;
            if (gg >= 0 && gg <= 3596) {
                const float4 v = *(const float4*)(xn + gg);
                f[4*b] = v.x; f[4*b+1] = v.y; f[4*b+2] = v.z; f[4*b+3] = v.w;
            } else {
                f[4*b] = 0.f; f[4*b+1] = 0.f; f[4*b+2] = 0.f; f[4*b+3] = 0.f;
            }
        }
        #pragma unroll
        for (int ch = 0; ch < 8; ++ch) {
            float acc[12];
            #pragma unroll
            for (int j = 0; j < 12; ++j) acc[j] = 0.f;
            #pragma unroll
            for (int k = 0; k < 16; ++k) {
                const float wk = wgs[ch * 16 + k];
                #pragma unroll
                for (int j = 0; j < 12; ++j)
                    acc[j] = fmaf(f[2*j + 1 + k], wk, acc[j]);
            }
            const float lo  = fmaxf(fmaxf(acc[0], acc[1]), fmaxf(acc[2], acc[3]));
            const float mid = fmaxf(fmaxf(acc[4], acc[5]), fmaxf(acc[6], acc[7]));
            const float hi  = fmaxf(fmaxf(acc[8], acc[9]), fmaxf(acc[10], acc[11]));
            const float sc = a.wsc[ch];
            m0[ch] = fmaxf(lo, mid) * sc;
            m1[ch] = (r < 224) ? fmaxf(mid, hi) * sc : 0.f;
        }
        float* on = a.bufA + ((size_t)n * 449 + 2 * r) * 8;
        *(float4*)(on + 0) = make_float4(m0[0], m0[1], m0[2], m0[3]);
        *(float4*)(on + 4) = make_float4(m0[4], m0[5], m0[6], m0[7]);
        if (r < 224) {
            *(float4*)(on + 8)  = make_float4(m1[0], m1[1], m1[2], m1[3]);
            *(float4*)(on + 12) = make_float4(m1[4], m1[5], m1[6], m1[7]);
        }
    }
    #pragma unroll
    for (int ch = 0; ch < 8; ++ch) {
        double sS = (double)m0[ch] + (double)m1[ch];
        double s2 = (double)m0[ch] * m0[ch] + (double)m1[ch] * m1[ch];
        #pragma unroll
        for (int off = 32; off; off >>= 1) {
            sS += __shfl_down(sS, off);
            s2 += __shfl_down(s2, off);
        }
        if (l == 0) {
            atomicAdd(&sred[ch], sS);
            atomicAdd(&sred[8 + ch], s2);
        }
    }
    __syncthreads();
    if (tid < 16) {
        double* so = a.stats + (size_t)(n & (NSLOT - 1)) * 16;
        atomicAdd(&so[tid], sred[tid]);
    }
}

// ---------------- layers 2..7: INTEGER inter-layer tensors ------------------
// Inter-layer values are (float)m * ws with m a small integer. We now store
// m+OOFF as u8/u16 (bin2/3 u8; bin4..7 u16) and the CONSUMER reconstructs
// v = (float)(stored - IOFF) * wsc_prev[c] -- bit-identical f32 ops/operands
// to what the producer previously stored, so all downstream results are
// bit-exact. Cuts ~60 MB of inter-layer write+read traffic; smaller tensors
// now fit per-XCD L2. Stats stay integer (unchanged). conv1 output (real
// floats) is bin2's input and stays f32.
template <int CIN, int LIN, int O, int K, int STRIDE, int PAD,
          int PK, int PS, int LP, int WPP, int LPB, int NS, bool SF64,
          int IOFF, int OOFF>
__device__ __forceinline__ void bin_body(
    const void* __restrict__ xprev, const uint32_t* __restrict__ wm,
    const float* __restrict__ wsc, const float* __restrict__ wsc_prev,
    const double* __restrict__ stats_in,
    const float* __restrict__ gamma, const float* __restrict__ beta,
    const double cntInv, void* __restrict__ out, double* __restrict__ stats_out)
{
    constexpr int OL    = (O < 64) ? O : 64;
    constexpr int PO    = 64 / OL;
    constexpr int WPW   = 4 / NS;       // waves per sample
    constexpr int SPAN  = (PK - 1) * STRIDE + K;
    constexpr int QLEN  = WPW * LPB * PS * STRIDE + SPAN;
    constexpr int XM64A =
        (WPP == 2)   ? (QLEN + 3)
      : (CIN == 8)   ? ((QLEN + 48) + 7) / 8          // byte layout
      : (CIN == 12)  ? ((2 * (QLEN + 10)) + 7) / 8    // u16 layout
      : ((QLEN + 5) / 2 + 2);                         // u32 layout (CIN=32)
    constexpr int F     = 2 * CIN;
    constexpr int FW    = (F > 64) ? 128 : 64;
    constexpr int XBASE = (CIN == 8 || CIN == 12) ? 0
                        : (WPP == 1) ? -(PAD & 1) : 0;   // keeps (lo-XBASE) parity

    __shared__ uint64_t xmbuf[NS][XM64A];
    __shared__ long long foldU[4][FW];
    __shared__ int sS[4][O], sS2[4][O];

    const int tid  = threadIdx.x;
    const int wv   = tid >> 6;
    const int l    = tid & 63;
    const int sloc = wv / WPW;          // sample slot within block
    const int wvs  = wv % WPW;          // wave index within sample
    uint64_t* xm64 = xmbuf[sloc];
    uint32_t* xm32 = (uint32_t*)xm64;
    uint16_t* xm16 = (uint16_t*)xm64;
    uint8_t*  xm8  = (uint8_t*)xm64;

    const int n   = blockIdx.x * NS + sloc;
    const int lp0 = wvs * LPB;
    const int lp1 = (lp0 + LPB < LP) ? lp0 + LPB : LP;

    // previous-layer scale for value reconstruction (all lanes l<CIN)
    const float wpv = (l < CIN) ? wsc_prev[l] : 0.f;

    // ---- BN fold (batch-constant): once per block, 4 waves co-op ----
    {
        const long long* stI = (const long long*)stats_in;
        long long pa = 0, pb_ = 0;
        double da = 0.0;
        #pragma unroll
        for (int s8 = 0; s8 < 8; ++s8) {
            const int s = (wv << 3) + s8;
            if constexpr (SF64) {
                if (l < F) da += stats_in[s * F + l];
            } else {
                if (l < ((F < 64) ? F : 64)) pa += stI[s * F + l];
                if constexpr (F > 64) { if (l < F - 64) pb_ += stI[s * F + 64 + l]; }
            }
        }
        if constexpr (SF64) foldU[wv][l] = __double_as_longlong(da);
        else {
            foldU[wv][l] = pa;
            if constexpr (F > 64) foldU[wv][64 + l] = pb_;
        }
    }
    __syncthreads();
    float aA = 0.f, aB = 0.f;
    {
        double t0 = 0.0, t1 = 0.0;
        if constexpr (SF64) {
            double tot = 0.0;
            #pragma unroll
            for (int w = 0; w < 4; ++w) tot += __longlong_as_double(foldU[w][l]);
            t0 = tot;
            t1 = __shfl(tot, CIN + l);
        } else if constexpr (F > 64) {
            long long a0 = 0, a1 = 0;
            #pragma unroll
            for (int w = 0; w < 4; ++w) { a0 += foldU[w][l]; a1 += foldU[w][64 + l]; }
            t0 = (double)a0; t1 = (double)a1;
        } else {
            long long a0 = 0;
            #pragma unroll
            for (int w = 0; w < 4; ++w) a0 += foldU[w][l];
            const double tot = (double)a0;
            t0 = tot;
            t1 = __shfl(tot, CIN + l);
        }
        if (l < CIN) {
            double mean, E2;
            if constexpr (SF64) { mean = t0 * cntInv; E2 = t1 * cntInv; }
            else {
                const double w = (double)wpv;
                mean = w * t0 * cntInv; E2 = w * w * t1 * cntInv;
            }
            const double var = E2 - mean * mean;
            const double inv = 1.0 / sqrt(var + 1e-5);
            const double av  = (double)gamma[l] * inv;
            aA = (float)av;
            aB = (float)((double)beta[l] - mean * av);
        }
    }

    // ---- pack [0, LIN), WPW waves interleaved, fully unrolled ----
    if constexpr (CIN == 64) {
        // input: u16 (stored m + IOFF)
        const uint16_t* xp = (const uint16_t*)xprev + (size_t)n * LIN * 64;
        constexpr int STP = WPW * 4;
        constexpr int MAXIT = (LIN + STP - 1) / STP;
        const int sub = l & 15, grp = l >> 4;
        const float a0 = __shfl(aA, 4*sub),     b0 = __shfl(aB, 4*sub);
        const float a1 = __shfl(aA, 4*sub + 1), b1 = __shfl(aB, 4*sub + 1);
        const float a2 = __shfl(aA, 4*sub + 2), b2 = __shfl(aB, 4*sub + 2);
        const float a3 = __shfl(aA, 4*sub + 3), b3 = __shfl(aB, 4*sub + 3);
        const float p0 = __shfl(wpv, 4*sub),     p1 = __shfl(wpv, 4*sub + 1);
        const float p2 = __shfl(wpv, 4*sub + 2), p3 = __shfl(wpv, 4*sub + 3);
        #pragma unroll
        for (int it = 0; it < MAXIT; ++it) {
            const int pb = wvs * 4 + it * STP;
            const int pos = pb + grp;
            const bool valid = pos < LIN;
            const ushort4 s = *(const ushort4*)(xp + (size_t)(valid ? pos : 0) * 64 + 4*sub);
            const float v0 = (float)((int)s.x - IOFF) * p0;
            const float v1 = (float)((int)s.y - IOFF) * p1;
            const float v2 = (float)((int)s.z - IOFF) * p2;
            const float v3 = (float)((int)s.w - IOFF) * p3;
            const unsigned long long bal0 = __ballot(valid && (fmaf(a0, v0, b0) < 0.f));
            const unsigned long long bal1 = __ballot(valid && (fmaf(a1, v1, b1) < 0.f));
            const unsigned long long bal2 = __ballot(valid && (fmaf(a2, v2, b2) < 0.f));
            const unsigned long long bal3 = __ballot(valid && (fmaf(a3, v3, b3) < 0.f));
            if (l < 4 && pb + l < LIN) {
                const uint64_t m = ((bal0 >> (16*l)) & 0xFFFFull)
                                 | (((bal1 >> (16*l)) & 0xFFFFull) << 16)
                                 | (((bal2 >> (16*l)) & 0xFFFFull) << 32)
                                 | (((bal3 >> (16*l)) & 0xFFFFull) << 48);
                xm64[pb + l - XBASE] = m;
            }
        }
    } else if constexpr (CIN == 32) {
        // input: u8 (stored m + IOFF)
        const uint8_t* xp = (const uint8_t*)xprev + (size_t)n * LIN * 32;
        constexpr int STP = WPW * 8;
        constexpr int MAXIT = (LIN + STP - 1) / STP;
        const int sub = l & 7, grp = l >> 3;
        const float a0 = __shfl(aA, 4*sub),     b0 = __shfl(aB, 4*sub);
        const float a1 = __shfl(aA, 4*sub + 1), b1 = __shfl(aB, 4*sub + 1);
        const float a2 = __shfl(aA, 4*sub + 2), b2 = __shfl(aB, 4*sub + 2);
        const float a3 = __shfl(aA, 4*sub + 3), b3 = __shfl(aB, 4*sub + 3);
        const float p0 = __shfl(wpv, 4*sub),     p1 = __shfl(wpv, 4*sub + 1);
        const float p2 = __shfl(wpv, 4*sub + 2), p3 = __shfl(wpv, 4*sub + 3);
        #pragma unroll
        for (int it = 0; it < MAXIT; ++it) {
            const int pb = wvs * 8 + it * STP;
            const int pos = pb + grp;
            const bool valid = pos < LIN;
            const uchar4 s = *(const uchar4*)(xp + (size_t)(valid ? pos : 0) * 32 + 4*sub);
            const float v0 = (float)((int)s.x - IOFF) * p0;
            const float v1 = (float)((int)s.y - IOFF) * p1;
            const float v2 = (float)((int)s.z - IOFF) * p2;
            const float v3 = (float)((int)s.w - IOFF) * p3;
            const unsigned long long bal0 = __ballot(valid && (fmaf(a0, v0, b0) < 0.f));
            const unsigned long long bal1 = __ballot(valid && (fmaf(a1, v1, b1) < 0.f));
            const unsigned long long bal2 = __ballot(valid && (fmaf(a2, v2, b2) < 0.f));
            const unsigned long long bal3 = __ballot(valid && (fmaf(a3, v3, b3) < 0.f));
            if (l < 8 && pb + l < LIN) {
                const uint32_t m = (uint32_t)((bal0 >> (8*l)) & 0xFFull)
                                 | ((uint32_t)((bal1 >> (8*l)) & 0xFFull) << 8)
                                 | ((uint32_t)((bal2 >> (8*l)) & 0xFFull) << 16)
                                 | ((uint32_t)((bal3 >> (8*l)) & 0xFFull) << 24);
                xm32[pb + l - XBASE] = m;
            }
        }
    } else if constexpr (CIN == 8) {
        // input: FLOAT (conv1 output)
        const float* xn = (const float*)xprev + (size_t)n * LIN * 8;
        constexpr int STP = WPW * 32;
        constexpr int MAXIT = (LIN + STP - 1) / STP;
        const int sub = l & 1, grp = l >> 1;
        const float a0 = __shfl(aA, 4*sub),     b0 = __shfl(aB, 4*sub);
        const float a1 = __shfl(aA, 4*sub + 1), b1 = __shfl(aB, 4*sub + 1);
        const float a2 = __shfl(aA, 4*sub + 2), b2 = __shfl(aB, 4*sub + 2);
        const float a3 = __shfl(aA, 4*sub + 3), b3 = __shfl(aB, 4*sub + 3);
        #pragma unroll
        for (int it = 0; it < MAXIT; ++it) {
            const int pb = wvs * 32 + it * STP;
            const int pos = pb + grp;
            const bool valid = pos < LIN;
            const float4 v = *(const float4*)(xn + (size_t)(valid ? pos : 0) * 8 + 4*sub);
            const unsigned long long bal0 = __ballot(valid && (fmaf(a0, v.x, b0) < 0.f));
            const unsigned long long bal1 = __ballot(valid && (fmaf(a1, v.y, b1) < 0.f));
            const unsigned long long bal2 = __ballot(valid && (fmaf(a2, v.z, b2) < 0.f));
            const unsigned long long bal3 = __ballot(valid && (fmaf(a3, v.w, b3) < 0.f));
            if (l < 32 && pb + l < LIN) {
                const uint32_t t0 = (uint32_t)((bal0 >> (2*l)) & 3ull);
                const uint32_t t1 = (uint32_t)((bal1 >> (2*l)) & 3ull);
                const uint32_t t2 = (uint32_t)((bal2 >> (2*l)) & 3ull);
                const uint32_t t3 = (uint32_t)((bal3 >> (2*l)) & 3ull);
                const uint32_t m = (t0 & 1) | ((t1 & 1) << 1) | ((t2 & 1) << 2) | ((t3 & 1) << 3)
                                 | ((t0 >> 1) << 4) | ((t1 >> 1) << 5) | ((t2 >> 1) << 6) | ((t3 >> 1) << 7);
                xm8[pb + l - XBASE] = (uint8_t)m;     // BYTE layout
            }
        }
    } else {   // CIN == 12: input u8, u16 mask layout
        const uint8_t* xp = (const uint8_t*)xprev + (size_t)n * LIN * 12;
        constexpr int PPW = 64 / CIN;
        constexpr int STP = WPW * PPW;
        constexpr int MAXIT = (LIN + STP - 1) / STP;
        const int pw = l / CIN, c = l - pw * CIN;
        const float myA = __shfl(aA, c), myB = __shfl(aB, c);
        const float myP = __shfl(wpv, c);
        const bool lact = (pw < PPW);
        #pragma unroll
        for (int it = 0; it < MAXIT; ++it) {
            const int pb = wvs * PPW + it * STP;
            const int pos = pb + pw;
            const bool act = lact && (pos < LIN) && (pb < LIN);
            float v = 0.f;
            if (act) v = fmaf(myA, (float)((int)xp[(size_t)pb * 12 + l] - IOFF) * myP, myB);
            const unsigned long long bal = __ballot(act && (v < 0.f));
            if (act && c == 0) {
                const uint32_t mk = (uint32_t)((bal >> (pw * CIN)) & ((1u << CIN) - 1));
                xm16[pos - XBASE] = (uint16_t)mk;
            }
        }
    }
    __syncthreads();

    // ---- conv + pool + integer stats over this wave's [lp0, lp1) ----
    if constexpr (WPP == 2) {
        uint16_t* on16 = (uint16_t*)out + (size_t)n * LP * O;
        const uint64_t* wmp = (const uint64_t*)wm;
        uint64_t wr[K];
        #pragma unroll
        for (int k = 0; k < K; ++k) wr[k] = wmp[l * K + k];
        uint64_t wr2[K];
        const int oo2 = 64 + ((O > 64 && l < O - 64) ? l : 0);
        if constexpr (O > 64) {
            #pragma unroll
            for (int k = 0; k < K; ++k) wr2[k] = wmp[oo2 * K + k];
        }
        int accS = 0, accS2 = 0, accSb = 0, accS2b = 0;

        #pragma unroll
        for (int li = 0; li < LPB; ++li) {
            const int lp = lp0 + li;
            if (lp < lp1) {
                const int lo = lp * PS * STRIDE - PAD;
                int m = -1000000, m2 = -1000000;
                if (lo >= 0 && lo + SPAN <= LIN) {
                    uint64_t tw[SPAN];
                    #pragma unroll
                    for (int t = 0; t < SPAN; ++t) tw[t] = xm64[lo - XBASE + t];
                    #pragma unroll
                    for (int j = 0; j < PK; ++j) {
                        int p = 0;
                        #pragma unroll
                        for (int k = 0; k < K; ++k)
                            p += __popcll(tw[j * STRIDE + k] ^ wr[k]);
                        m = max(m, CIN * K - 2 * p);
                        if constexpr (O > 64) {
                            int p2 = 0;
                            #pragma unroll
                            for (int k = 0; k < K; ++k)
                                p2 += __popcll(tw[j * STRIDE + k] ^ wr2[k]);
                            m2 = max(m2, CIN * K - 2 * p2);
                        }
                    }
                } else {
                    #pragma unroll
                    for (int j = 0; j < PK; ++j) {
                        const int base = lo + j * STRIDE;
                        int p = 0, nv = 0, p2 = 0;
                        #pragma unroll
                        for (int k = 0; k < K; ++k) {
                            const int q = base + k;
                            if (q >= 0 && q < LIN) {
                                ++nv;
                                const uint64_t xv = xm64[q - XBASE];
                                p += __popcll(xv ^ wr[k]);
                                if constexpr (O > 64) p2 += __popcll(xv ^ wr2[k]);
                            }
                        }
                        m = max(m, CIN * nv - 2 * p);
                        if constexpr (O > 64) m2 = max(m2, CIN * nv - 2 * p2);
                    }
                }
                on16[lp * O + l] = (uint16_t)(m + OOFF);
                accS += m; accS2 += m * m;
                if constexpr (O > 64) {
                    if (l < O - 64) {
                        on16[lp * O + 64 + l] = (uint16_t)(m2 + OOFF);
                        accSb += m2; accS2b += m2 * m2;
                    }
                }
            }
        }
        sS[wv][l] = accS; sS2[wv][l] = accS2;
        if constexpr (O > 64) {
            if (l < O - 64) { sS[wv][64 + l] = accSb; sS2[wv][64 + l] = accS2b; }
        }
    } else if constexpr (CIN == 8) {
        // bin2: byte mask layout, 3 popc32/window; OUTPUT u8 (m + OOFF)
        uint8_t* on8 = (uint8_t*)out + (size_t)n * LP * O;
        const int po = l / OL, oo = l - po * OL;     // OL=12, PO=5
        const bool cact = (po < PO);
        const int osel = cact ? oo : 0;
        const uint32_t wr0 = wm[osel*3], wr1 = wm[osel*3+1], wr2 = wm[osel*3+2];
        uint32_t wb[12];
        #pragma unroll
        for (int k = 0; k < 12; ++k)
            wb[k] = ((k < 4 ? wr0 : (k < 8 ? wr1 : wr2)) >> (8 * (k & 3))) & 255u;
        const uint32_t* xw = (const uint32_t*)xm64;
        int accS = 0, accS2 = 0;

        #pragma unroll 2
        for (int lp = lp0 + po; lp < lp1; lp += PO) {
            const int lo = lp * PS * STRIDE - PAD;   // = 4lp-5, ≡3 mod 4
            int m = -1000000;
            if (lo >= 0 && lo + SPAN <= LIN) {
                const int bb = lo - XBASE;           // ≡3 mod 4
                const int w0 = bb >> 2;
                uint32_t tw[6];
                #pragma unroll
                for (int i = 0; i < 6; ++i) tw[i] = xw[w0 + i];
                #pragma unroll
                for (int j = 0; j < PK; ++j) {
                    const int wo = (j + 1) >> 1;     // 0,1,1,2
                    uint32_t e0, e1, e2;
                    if (j & 1) {                     // shift 8
                        e0 = (tw[wo]   >> 8) | (tw[wo+1] << 24);
                        e1 = (tw[wo+1] >> 8) | (tw[wo+2] << 24);
                        e2 = (tw[wo+2] >> 8) | (tw[wo+3] << 24);
                    } else {                         // shift 24
                        e0 = (tw[wo]   >> 24) | (tw[wo+1] << 8);
                        e1 = (tw[wo+1] >> 24) | (tw[wo+2] << 8);
                        e2 = (tw[wo+2] >> 24) | (tw[wo+3] << 8);
                    }
                    const int p = __popc(e0 ^ wr0) + __popc(e1 ^ wr1) + __popc(e2 ^ wr2);
                    m = max(m, 96 - 2 * p);
                }
            } else {
                #pragma unroll
                for (int j = 0; j < PK; ++j) {
                    const int base = lo + j * STRIDE;
                    int p = 0, nv = 0;
                    #pragma unroll
                    for (int k = 0; k < 12; ++k) {
                        const int q = base + k;
                        if (q >= 0 && q < LIN) { ++nv; p += __popc((uint32_t)xm8[q - XBASE] ^ wb[k]); }
                    }
                    m = max(m, 8 * nv - 2 * p);
                }
            }
            if (cact) {
                on8[lp * O + oo] = (uint8_t)(m + OOFF);
                accS += m; accS2 += m * m;
            }
        }
        int t = accS, t2 = accS2;
        #pragma unroll
        for (int g = 1; g < PO; ++g) {
            t  += __shfl(accS,  l + g * OL);
            t2 += __shfl(accS2, l + g * OL);
        }
        if (l < OL) { sS[wv][l] = t; sS2[wv][l] = t2; }
        else if (l < O) { sS[wv][l] = 0; sS2[wv][l] = 0; }
    } else if constexpr (CIN == 12) {
        // bin3: u16 mask layout, 5 popc32/window; OUTPUT u8 (m + OOFF)
        uint8_t* on8 = (uint8_t*)out + (size_t)n * LP * O;
        const int po = l / OL, oo = l - po * OL;     // OL=32, PO=2
        const bool cact = (po < PO);
        const int osel = cact ? oo : 0;
        uint32_t wE[5], wO[5];
        #pragma unroll
        for (int g = 0; g < 5; ++g) { wE[g] = wm[osel*10 + g]; wO[g] = wm[osel*10 + 5 + g]; }
        uint32_t we16[9];
        we16[0]=wE[0]&0xFFFFu; we16[1]=wE[0]>>16; we16[2]=wE[1]&0xFFFFu; we16[3]=wE[1]>>16;
        we16[4]=wE[2]&0xFFFFu; we16[5]=wE[2]>>16; we16[6]=wE[3]&0xFFFFu; we16[7]=wE[3]>>16;
        we16[8]=wE[4]&0xFFFFu;
        const uint32_t* xw = (const uint32_t*)xm64;
        int accS = 0, accS2 = 0;

        #pragma unroll 2
        for (int lp = lp0 + po; lp < lp1; lp += PO) {
            const int lo = lp * PS * STRIDE - PAD;   // = 2lp-4, even
            int m = -1000000;
            if (lo >= 0 && lo + SPAN <= LIN) {
                const int s0 = (lo - XBASE) >> 1;    // (lo-XBASE) even
                uint32_t tw[7];
                #pragma unroll
                for (int i = 0; i < 7; ++i) tw[i] = xw[s0 + i];
                #pragma unroll
                for (int j = 0; j < PK; ++j) {
                    const int o_ = j >> 1;
                    int p;
                    if (j & 1)
                        p = __popc((tw[o_] & 0xFFFF0000u) ^ wO[0]) + __popc(tw[o_+1] ^ wO[1])
                          + __popc(tw[o_+2] ^ wO[2]) + __popc(tw[o_+3] ^ wO[3])
                          + __popc(tw[o_+4] ^ wO[4]);
                    else
                        p = __popc(tw[o_] ^ wE[0]) + __popc(tw[o_+1] ^ wE[1])
                          + __popc(tw[o_+2] ^ wE[2]) + __popc(tw[o_+3] ^ wE[3])
                          + __popc((tw[o_+4] & 0xFFFFu) ^ wE[4]);
                    m = max(m, 108 - 2 * p);
                }
            } else {
                #pragma unroll
                for (int j = 0; j < PK; ++j) {
                    const int base = lo + j * STRIDE;
                    int p = 0, nv = 0;
                    #pragma unroll
                    for (int k = 0; k < 9; ++k) {
                        const int q = base + k;
                        if (q >= 0 && q < LIN) { ++nv; p += __popc((uint32_t)xm16[q - XBASE] ^ we16[k]); }
                    }
                    m = max(m, 12 * nv - 2 * p);
                }
            }
            if (cact) {
                on8[lp * O + oo] = (uint8_t)(m + OOFF);
                accS += m; accS2 += m * m;
            }
        }
        int t = accS, t2 = accS2;
        #pragma unroll
        for (int g = 1; g < PO; ++g) {
            t  += __shfl(accS,  l + g * OL);
            t2 += __shfl(accS2, l + g * OL);
        }
        if (l < OL) { sS[wv][l] = t; sS2[wv][l] = t2; }
    } else {
        // bin4 (CIN=32, O=64, PO=1): u32-mask path; OUTPUT u16 (m + OOFF)
        uint16_t* on16 = (uint16_t*)out + (size_t)n * LP * O;
        const int po = l / OL, oo = l - po * OL;
        const bool cact = (po < PO);
        uint32_t wr[K];
        #pragma unroll
        for (int k = 0; k < K; ++k) wr[k] = wm[(cact ? oo : 0) * K + k];
        int accS = 0, accS2 = 0;

        constexpr int PAIRS = (SPAN + 1) / 2;
        #pragma unroll 2
        for (int lp = lp0 + po; lp < lp1; lp += PO) {
            const int lo = lp * PS * STRIDE - PAD;   // (lo - XBASE) even
            int m = -1000000;
            if (lo >= 0 && lo + SPAN <= LIN) {
                uint32_t tw[PAIRS * 2];
                const int e0 = (lo - XBASE) >> 1;
                #pragma unroll
                for (int i = 0; i < PAIRS; ++i) {
                    const uint64_t u64v = xm64[e0 + i];
                    tw[2 * i]     = (uint32_t)u64v;
                    tw[2 * i + 1] = (uint32_t)(u64v >> 32);
                }
                #pragma unroll
                for (int j = 0; j < PK; ++j) {
                    int p = 0;
                    #pragma unroll
                    for (int k = 0; k < K; ++k)
                        p += __popc(tw[j * STRIDE + k] ^ wr[k]);
                    m = max(m, CIN * K - 2 * p);
                }
            } else {
                #pragma unroll
                for (int j = 0; j < PK; ++j) {
                    const int base = lo + j * STRIDE;
                    int p = 0, nv = 0;
                    #pragma unroll
                    for (int k = 0; k < K; ++k) {
                        const int q = base + k;
                        if (q >= 0 && q < LIN) { ++nv; p += __popc(xm32[q - XBASE] ^ wr[k]); }
                    }
                    m = max(m, CIN * nv - 2 * p);
                }
            }
            if (cact) {
                on16[lp * O + oo] = (uint16_t)(m + OOFF);
                accS += m; accS2 += m * m;
            }
        }
        int t = accS, t2 = accS2;
        #pragma unroll
        for (int g = 1; g < PO; ++g) {
            t  += __shfl(accS,  l + g * OL);
            t2 += __shfl(accS2, l + g * OL);
        }
        if (l < OL) { sS[wv][l] = t; sS2[wv][l] = t2; }
    }
    __syncthreads();

    // ---- one int64 atomic set per block (slot choice free: fold sums all) --
    const int slot = ((NS == 1) ? n : (int)blockIdx.x) & (NSLOT - 1);
    unsigned long long* soU =
        (unsigned long long*)stats_out + (size_t)slot * 2 * O;
    for (int t = tid; t < 2 * O; t += 256) {
        int tot;
        if (t < O) tot = sS[0][t] + sS[1][t] + sS[2][t] + sS[3][t];
        else { const int f = t - O; tot = sS2[0][f] + sS2[1][f] + sS2[2][f] + sS2[3][f]; }
        atomicAdd(&soU[t], (unsigned long long)(long long)tot);
    }
}

#define BIN_PARAMS \
    const void* __restrict__ xprev, const uint32_t* __restrict__ wm, \
    const float* __restrict__ wsc, const float* __restrict__ wsc_prev, \
    const double* __restrict__ stats_in, \
    const float* __restrict__ gamma, const float* __restrict__ beta, \
    const double cntInv, void* __restrict__ out, double* __restrict__ stats_out
#define BIN_ARGS xprev, wm, wsc, wsc_prev, stats_in, gamma, beta, cntInv, out, stats_out

__global__ __launch_bounds__(256) void k_bin2(BIN_PARAMS) { bin_body< 8,449,12,12,2,5,4,2,111,1,28,1,true ,  0, 96>(BIN_ARGS); }
__global__ __launch_bounds__(256) void k_bin3(BIN_PARAMS) { bin_body<12,111,32, 9,1,4,5,2, 54,1,14,1,false, 96,108>(BIN_ARGS); }
__global__ __launch_bounds__(256) void k_bin4(BIN_PARAMS) { bin_body<32, 54,64, 7,1,3,4,2, 26,1, 7,1,false,108,224>(BIN_ARGS); }
__global__ __launch_bounds__(256) void k_bin5(BIN_PARAMS) { bin_body<64, 26,64, 5,1,2,2,2, 13,2, 7,2,false,224,320>(BIN_ARGS); }
__global__ __launch_bounds__(256) void k_bin6(BIN_PARAMS) { bin_body<64, 13,64, 3,1,1,2,2,  6,2, 3,2,false,320,192>(BIN_ARGS); }
__global__ __launch_bounds__(256) void k_bin7(BIN_PARAMS) { bin_body<64,  6,72, 3,1,1,2,2,  3,2, 2,2,false,192,192>(BIN_ARGS); }

// ---------------- FC, wave-per-sample, 4 samples per block ------------------
// Layer-7 values reconstructed from u16: v = (float)(s - 192) * wsc[244+c]
// (bit-identical to the f32 value bin7 previously stored).
__global__ __launch_bounds__(256) void k_fc(Args a) {
    const int n = blockIdx.x * 4 + (int)(threadIdx.x >> 6);
    const int l = (int)(threadIdx.x & 63);
    const long long* st = (const long long*)(a.stats + 15616);
    long long s = 0, s2 = 0, sb = 0, s2b = 0;
    #pragma unroll 4
    for (int sl = 0; sl < NSLOT; ++sl) {
        s  += st[sl * 144 + l];
        s2 += st[sl * 144 + 72 + l];
        if (l < 8) {
            sb  += st[sl * 144 + 64 + l];
            s2b += st[sl * 144 + 72 + 64 + l];
        }
    }
    const float w7  = a.wsc[244 + l];
    const float w7b = (l < 8) ? a.wsc[244 + 64 + l] : 0.f;
    float aA0, aB0, aA1 = 0.f, aB1 = 0.f;
    {
        const double w = (double)w7;
        const double mean = w * (double)s / 6144.0;
        const double E2   = w * w * (double)s2 / 6144.0;
        const double var  = E2 - mean * mean;
        const double inv  = 1.0 / sqrt(var + 1e-5);
        const double aa   = (double)a.G[6][l] * inv;
        aA0 = (float)aa; aB0 = (float)((double)a.Bt[6][l] - mean * aa);
    }
    if (l < 8) {
        const double w = (double)w7b;
        const double mean = w * (double)sb / 6144.0;
        const double E2   = w * w * (double)s2b / 6144.0;
        const double var  = E2 - mean * mean;
        const double inv  = 1.0 / sqrt(var + 1e-5);
        const double aa   = (double)a.G[6][64 + l] * inv;
        aA1 = (float)aa; aB1 = (float)((double)a.Bt[6][64 + l] - mean * aa);
    }
    const uint16_t* p7 = (const uint16_t*)a.bufA + (size_t)n * 216;
    float acc[5] = {0.f, 0.f, 0.f, 0.f, 0.f};
    #pragma unroll
    for (int j = 0; j < 4; ++j) {
        const int i = l + 64 * j;
        const int ic = (i < 216) ? i : 215;
        const int c = ic / 3, lp = ic - 3 * c;       // flatten is [72,3]
        float aa = __shfl(aA0, c);
        float bb = __shfl(aB0, c);
        float ww = __shfl(w7, c);
        const float aaH = __shfl(aA1, c - 64);
        const float bbH = __shfl(aB1, c - 64);
        const float wwH = __shfl(w7b, c - 64);
        if (c >= 64) { aa = aaH; bb = bbH; ww = wwH; }
        if (i < 216) {
            const float v = (float)((int)p7[lp * 72 + c] - 192) * ww;
            const float av = signf(fmaf(aa, v, bb));
            #pragma unroll
            for (int o = 0; o < 5; ++o)
                acc[o] += av * signf(a.WFC[o * 216 + i]);
        }
    }
    #pragma unroll
    for (int o = 0; o < 5; ++o) {
        float v = acc[o];
        #pragma unroll
        for (int off = 32; off; off >>= 1) v += __shfl_down(v, off);
        if (l == 0) a.out[(size_t)n * 5 + o] = v * a.wsc[316 + o];
    }
}

extern "C" void kernel_launch(void* const* d_in, const int* in_sizes, int n_in,
                              void* d_out, int out_size, void* d_ws, size_t ws_size,
                              hipStream_t stream) {
    Args a;
    a.x = (const float*)d_in[0];
    for (int i = 0; i < 7; ++i) {
        a.W[i]  = (const float*)d_in[1 + 3 * i];
        a.G[i]  = (const float*)d_in[2 + 3 * i];
        a.Bt[i] = (const float*)d_in[3 + 3 * i];
    }
    a.WFC = (const float*)d_in[22];
    a.out = (float*)d_out;

    char* ws = (char*)d_ws;
    a.bufA  = (float*)ws;                       // conv1 f32 29.4MB; later bin3 u8 / bin5 u16 / bin7 u16
    a.bufB  = (float*)(ws + 29425664);          // bin2 u8 2.7MB / bin4 u16 6.8MB / bin6 u16 1.6MB
    a.stats = (double*)(ws + 43057152);         // 20224 slots
    a.wsc   = (float*)(ws + 43218944);          // 1284 B
    a.wmb   = (uint32_t*)d_out;                 // 9040 B, dead before fc writes

    k_setup<<<391, 256, 0, stream>>>(a);
    k_conv1<<<NBATCH, 256, 0, stream>>>(a);
    // stats (8B units): L1@0, L2@512, L3@1280, L4@3328, L5@7424, L6@11520, L7@15616
    k_bin2<<<dim3(NBATCH, 1), 256, 0, stream>>>(
        a.bufA, a.wmb + 0, a.wsc + 8, a.wsc, a.stats + 0, a.G[0], a.Bt[0],
        1.0/919552.0, a.bufB, a.stats + 512);
    k_bin3<<<dim3(NBATCH, 1), 256, 0, stream>>>(
        a.bufB, a.wmb + 36, a.wsc + 20, a.wsc + 8, a.stats + 512, a.G[1], a.Bt[1],
        1.0/227328.0, a.bufA, a.stats + 1280);
    k_bin4<<<dim3(NBATCH, 1), 256, 0, stream>>>(
        a.bufA, a.wmb + 356, a.wsc + 52, a.wsc + 20, a.stats + 1280, a.G[2], a.Bt[2],
        1.0/110592.0, a.bufB, a.stats + 3328);
    k_bin5<<<dim3(NBATCH / 2, 1), 256, 0, stream>>>(
        a.bufB, a.wmb + 804, a.wsc + 116, a.wsc + 52, a.stats + 3328, a.G[3], a.Bt[3],
        1.0/53248.0, a.bufA, a.stats + 7424);
    k_bin6<<<dim3(NBATCH / 2, 1), 256, 0, stream>>>(
        a.bufA, a.wmb + 1444, a.wsc + 180, a.wsc + 116, a.stats + 7424, a.G[4], a.Bt[4],
        1.0/26624.0, a.bufB, a.stats + 11520);
    k_bin7<<<dim3(NBATCH / 2, 1), 256, 0, stream>>>(
        a.bufB, a.wmb + 1828, a.wsc + 244, a.wsc + 180, a.stats + 11520, a.G[5], a.Bt[5],
        1.0/12288.0, a.bufA, a.stats + 15616);
    k_fc<<<NBATCH / 4, 256, 0, stream>>>(a);
}